// Round 1
// baseline (1409.950 us; speedup 1.0000x reference)
//
#include <hip/hip_runtime.h>

// Problem constants (fixed by reference): B=2, N=8192, C=80
constexpr int NB = 2;
constexpr int NN = 8192;
constexpr int NC = 80;

// d_out layout (floats), in reference return order:
// boxes[B,N,4], max_scores[B,N], labels[B,N], keep[B,N], all_scores[B,N,C]
constexpr size_t OFF_BOXES  = 0;
constexpr size_t OFF_SCORES = (size_t)NB * NN * 4;            // 65536
constexpr size_t OFF_LABELS = OFF_SCORES + (size_t)NB * NN;   // 81920
constexpr size_t OFF_KEEP   = OFF_LABELS + (size_t)NB * NN;   // 98304
constexpr size_t OFF_ALL    = OFF_KEEP + (size_t)NB * NN;     // 114688

// d_ws layout
constexpr size_t WS_KEYS  = 0;                                  // B*N u64
constexpr size_t WS_VBYTE = WS_KEYS + (size_t)NB * NN * 8;      // B*N u8
constexpr size_t WS_ORDER = WS_VBYTE + (size_t)NB * NN;         // B*N i32
constexpr size_t WS_SBOX  = WS_ORDER + (size_t)NB * NN * 4;     // B*N float4
constexpr size_t WS_VBITS = WS_SBOX + (size_t)NB * NN * 16;     // B*128 u64
constexpr size_t WS_MASK  = WS_VBITS + (size_t)NB * 128 * 8;    // B*N*128 u64
constexpr size_t WS_TOTAL = WS_MASK + (size_t)NB * NN * 128 * 8; // ~17.25 MB

__device__ inline unsigned long long shfl64(unsigned long long v, int src) {
  int lo = __shfl((int)(unsigned int)(v & 0xffffffffull), src, 64);
  int hi = __shfl((int)(unsigned int)(v >> 32), src, 64);
  return ((unsigned long long)(unsigned int)hi << 32) | (unsigned int)lo;
}

// IoU exactly mirroring the numpy op order; contraction off so f32 rounding
// matches numpy bit-for-bit (keep bits tolerate no error).
__device__ inline float iou_pair(const float4 p, const float4 q) {
#pragma clang fp contract(off)
  float areaA = (p.z - p.x) * (p.w - p.y);
  float areaB = (q.z - q.x) * (q.w - q.y);
  float ix1 = fmaxf(p.x, q.x);
  float iy1 = fmaxf(p.y, q.y);
  float ix2 = fminf(p.z, q.z);
  float iy2 = fminf(p.w, q.w);
  float inter = fmaxf(ix2 - ix1, 0.0f) * fmaxf(iy2 - iy1, 0.0f);
  float uni = areaA + areaB - inter;
  return inter / fmaxf(uni, 1e-9f);
}

__device__ inline float clip01(float v) { return fminf(fmaxf(v, 0.0f), 1.0f); }

// One wave per (b,n): sigmoid all 80 classes, max/argmax (first-index ties),
// box decode, validity, sort key.
__global__ __launch_bounds__(256) void decode_kernel(
    const float* __restrict__ logits, const float4* __restrict__ deltas,
    const float4* __restrict__ anchors, float4* __restrict__ boxes_out,
    float* __restrict__ scores_out, float* __restrict__ labels_out,
    float* __restrict__ all_out, unsigned long long* __restrict__ keys,
    unsigned char* __restrict__ vbyte) {
#pragma clang fp contract(off)
  int wid = (blockIdx.x * 256 + threadIdx.x) >> 6;  // 0 .. B*N-1
  int lane = threadIdx.x & 63;
  int n = wid & (NN - 1);
  size_t base = (size_t)wid * NC;

  float x0 = logits[base + lane];
  float sig0 = 1.0f / (1.0f + expf(-x0));
  all_out[base + lane] = sig0;
  float bs = sig0;
  int bidx = lane;
  if (lane < NC - 64) {
    float x1 = logits[base + 64 + lane];
    float sig1 = 1.0f / (1.0f + expf(-x1));
    all_out[base + 64 + lane] = sig1;
    if (sig1 > bs) { bs = sig1; bidx = lane + 64; }  // tie -> smaller idx wins
  }
  for (int off = 32; off; off >>= 1) {
    float os = __shfl_xor(bs, off, 64);
    int oi = __shfl_xor(bidx, off, 64);
    if (os > bs || (os == bs && oi < bidx)) { bs = os; bidx = oi; }
  }
  if (lane == 0) {
    float4 d = deltas[wid];
    float4 a = anchors[n];
    float aw = a.z - a.x, ah = a.w - a.y;
    float acx = a.x + 0.5f * aw, acy = a.y + 0.5f * ah;
    float dw = fminf(d.z, 4.0f), dh = fminf(d.w, 4.0f);
    float pcx = d.x * aw + acx;
    float pcy = d.y * ah + acy;
    float pw = expf(dw) * aw;
    float ph = expf(dh) * ah;
    float4 bx;
    bx.x = clip01(pcx - 0.5f * pw);
    bx.y = clip01(pcy - 0.5f * ph);
    bx.z = clip01(pcx + 0.5f * pw);
    bx.w = clip01(pcy + 0.5f * ph);
    boxes_out[wid] = bx;
    scores_out[wid] = bs;
    labels_out[wid] = (float)bidx;
    float bw = bx.z - bx.x, bh = bx.w - bx.y;
    bool valid = (bs > 0.5f) && (bw > 0.01f) && (bh > 0.01f) &&
                 (bw < 0.99f) && (bh < 0.99f);
    vbyte[wid] = valid ? 1 : 0;
    // score bits monotone (score>0); tie-break: smaller n first under
    // DESCENDING key sort -> use (N-1-n) in low bits.
    keys[wid] = ((unsigned long long)__float_as_uint(bs) << 32) |
                (unsigned int)(NN - 1 - n);
  }
}

// Per-batch bitonic sort (descending) of 8192 u64 keys in LDS; then emit
// order[], gathered sorted boxes, and valid bitmask in sorted order.
__global__ __launch_bounds__(1024) void sort_kernel(
    const unsigned long long* __restrict__ keys_in,
    const float4* __restrict__ boxes, const unsigned char* __restrict__ vbyte,
    int* __restrict__ order, float4* __restrict__ sbox,
    unsigned long long* __restrict__ vbits) {
  __shared__ unsigned long long sk[NN];  // 64 KiB
  int b = blockIdx.x, tid = threadIdx.x;
  for (int p = tid; p < NN; p += 1024) sk[p] = keys_in[(size_t)b * NN + p];
  __syncthreads();
  for (int k = 2; k <= NN; k <<= 1) {
    for (int j = k >> 1; j > 0; j >>= 1) {
      for (int i = tid; i < NN; i += 1024) {
        int ixj = i ^ j;
        if (ixj > i) {
          unsigned long long a = sk[i], c = sk[ixj];
          bool up = (i & k) == 0;  // descending region
          if (up ? (a < c) : (a > c)) { sk[i] = c; sk[ixj] = a; }
        }
      }
      __syncthreads();
    }
  }
  for (int p = tid; p < NN; p += 1024) {
    unsigned long long key = sk[p];
    int idx = (NN - 1) - (int)(unsigned int)(key & 0xffffffffull);
    order[(size_t)b * NN + p] = idx;
    sbox[(size_t)b * NN + p] = boxes[(size_t)b * NN + idx];
    unsigned long long ball = __ballot(vbyte[(size_t)b * NN + idx] != 0);
    if ((tid & 63) == 0) vbits[b * 128 + (p >> 6)] = ball;
  }
}

// 64x64 tile of the (sorted-order) suppression matrix: bit j set in row i's
// word iff j>i and IoU>0.5. Upper triangle only.
__global__ __launch_bounds__(64) void build_kernel(
    const float4* __restrict__ sbox, unsigned long long* __restrict__ mask) {
  int bx = blockIdx.x, by = blockIdx.y, b = blockIdx.z;
  if (bx < by) return;
  int lane = threadIdx.x;
  __shared__ float4 cb[64];
  cb[lane] = sbox[(size_t)b * NN + bx * 64 + lane];
  __syncthreads();
  int i = by * 64 + lane;
  float4 rb = sbox[(size_t)b * NN + i];
  unsigned long long word = 0;
  int j0 = (bx == by) ? lane + 1 : 0;
  for (int jj = j0; jj < 64; ++jj)
    if (iou_pair(rb, cb[jj]) > 0.5f) word |= 1ull << jj;
  mask[((size_t)b * NN + i) * 128 + bx] = word;
}

// Sequential greedy reduce: one wave per batch. Lane l owns remv/keep words
// 2l and 2l+1. Per 64-chunk: uniform register bit-loop over candidates
// (iterations == kept-in-chunk), then batched OR of kept rows into future
// words (coalesced 8B/lane loads).
__global__ __launch_bounds__(64) void reduce_kernel(
    const unsigned long long* __restrict__ mask,
    const unsigned long long* __restrict__ vbits,
    const int* __restrict__ order, float* __restrict__ keep_out) {
  int b = blockIdx.x, lane = threadIdx.x;
  __shared__ int rowlist[64];
  unsigned long long remv0 = 0, remv1 = 0, kb0 = 0, kb1 = 0;
  unsigned long long vb0 = vbits[b * 128 + 2 * lane];
  unsigned long long vb1 = vbits[b * 128 + 2 * lane + 1];
  const unsigned long long* mb = mask + (size_t)b * NN * 128;
  int w0 = 2 * lane, w1 = 2 * lane + 1;

  for (int c = 0; c < 128; ++c) {
    int owner = c >> 1;
    unsigned long long rm = shfl64((c & 1) ? remv1 : remv0, owner);
    unsigned long long vbw = shfl64((c & 1) ? vb1 : vb0, owner);
    // diagonal word of row (c*64+lane)
    unsigned long long dw = mb[(size_t)(c * 64 + lane) * 128 + c];
    unsigned long long cand = vbw & ~rm;
    unsigned long long keptw = 0;
    while (cand) {  // uniform across lanes
      int bi = __builtin_ctzll(cand);
      unsigned long long rowdiag = shfl64(dw, bi);
      keptw |= 1ull << bi;
      rm |= rowdiag;
      cand = (cand & (cand - 1)) & ~rowdiag;
    }
    if (lane == owner) {
      if (c & 1) { remv1 = rm; kb1 = keptw; }
      else       { remv0 = rm; kb0 = keptw; }
    }
    int nk = __popcll(keptw);
    if (nk) {
      bool mine = (keptw >> lane) & 1;
      int pos = __popcll(keptw & ((1ull << lane) - 1));
      if (mine) rowlist[pos] = c * 64 + lane;
      __syncthreads();
      bool need0 = w0 > c, need1 = w1 > c;  // need1==false implies need0==false
      int g = 0;
      for (; g + 4 <= nk; g += 4) {
        unsigned long long a0 = 0, a1 = 0;
#pragma unroll
        for (int u = 0; u < 4; ++u) {
          const unsigned long long* rbp = mb + (size_t)rowlist[g + u] * 128;
          if (need1) {
            a1 |= rbp[w1];
            if (need0) a0 |= rbp[w0];
          }
        }
        remv0 |= a0;
        remv1 |= a1;
      }
      for (; g < nk; ++g) {
        const unsigned long long* rbp = mb + (size_t)rowlist[g] * 128;
        if (need1) {
          remv1 |= rbp[w1];
          if (need0) remv0 |= rbp[w0];
        }
      }
      __syncthreads();
    }
  }
  // scatter keep flags back to original anchor order
  for (int h = 0; h < 2; ++h) {
    int w = 2 * lane + h;
    unsigned long long kw = h ? kb1 : kb0;
    for (int t = 0; t < 64; ++t) {
      int orig = order[(size_t)b * NN + w * 64 + t];
      keep_out[(size_t)b * NN + orig] = ((kw >> t) & 1) ? 1.0f : 0.0f;
    }
  }
}

// Slow-but-correct fallback if d_ws can't hold the 16 MB mask: classic
// iterative greedy NMS, one block per batch.
__global__ __launch_bounds__(1024) void nms_fallback(
    const float4* __restrict__ sbox, const unsigned long long* __restrict__ vbits,
    const int* __restrict__ order, float* __restrict__ keep_out) {
  int b = blockIdx.x, tid = threadIdx.x;
  __shared__ unsigned long long dead[128];
  __shared__ int s_next;
  __shared__ float4 s_box;
  for (int w = tid; w < 128; w += 1024) dead[w] = ~vbits[b * 128 + w];
  for (int p = tid; p < NN; p += 1024)
    keep_out[(size_t)b * NN + order[(size_t)b * NN + p]] = 0.0f;
  __syncthreads();
  int i = 0;
  while (true) {
    if (tid == 0) {
      int nxt = NN;
      int w = i >> 6;
      unsigned long long live = ~dead[w] & (~0ull << (i & 63));
      while (true) {
        if (live) { nxt = w * 64 + __builtin_ctzll(live); break; }
        if (++w >= 128) break;
        live = ~dead[w];
      }
      s_next = nxt;
      if (nxt < NN) {
        s_box = sbox[(size_t)b * NN + nxt];
        keep_out[(size_t)b * NN + order[(size_t)b * NN + nxt]] = 1.0f;
      }
    }
    __syncthreads();
    i = s_next;
    if (i >= NN) break;
    float4 kb = s_box;
    for (int j = i + 1 + tid; j < NN; j += 1024) {
      if (iou_pair(kb, sbox[(size_t)b * NN + j]) > 0.5f)
        atomicOr(&dead[j >> 6], 1ull << (j & 63));
    }
    __syncthreads();
    i = i + 1;
  }
}

extern "C" void kernel_launch(void* const* d_in, const int* in_sizes, int n_in,
                              void* d_out, int out_size, void* d_ws, size_t ws_size,
                              hipStream_t stream) {
  const float* logits = (const float*)d_in[0];
  const float4* deltas = (const float4*)d_in[1];
  const float4* anchors = (const float4*)d_in[2];
  float* out = (float*)d_out;
  float4* boxes_out = (float4*)(out + OFF_BOXES);
  float* scores_out = out + OFF_SCORES;
  float* labels_out = out + OFF_LABELS;
  float* keep_out = out + OFF_KEEP;
  float* all_out = out + OFF_ALL;

  char* ws = (char*)d_ws;
  unsigned long long* keys = (unsigned long long*)(ws + WS_KEYS);
  unsigned char* vbyte = (unsigned char*)(ws + WS_VBYTE);
  int* order = (int*)(ws + WS_ORDER);
  float4* sbox = (float4*)(ws + WS_SBOX);
  unsigned long long* vbits = (unsigned long long*)(ws + WS_VBITS);
  unsigned long long* mask = (unsigned long long*)(ws + WS_MASK);

  decode_kernel<<<dim3(NB * NN / 4), dim3(256), 0, stream>>>(
      logits, deltas, anchors, boxes_out, scores_out, labels_out, all_out,
      keys, vbyte);
  sort_kernel<<<dim3(NB), dim3(1024), 0, stream>>>(
      keys, (const float4*)boxes_out, vbyte, order, sbox, vbits);
  if (ws_size >= WS_TOTAL) {
    build_kernel<<<dim3(128, 128, NB), dim3(64), 0, stream>>>(sbox, mask);
    reduce_kernel<<<dim3(NB), dim3(64), 0, stream>>>(mask, vbits, order, keep_out);
  } else {
    nms_fallback<<<dim3(NB), dim3(1024), 0, stream>>>(sbox, vbits, order, keep_out);
  }
}

// Round 2
// 617.096 us; speedup vs baseline: 2.2848x; 2.2848x over previous
//
#include <hip/hip_runtime.h>

// Problem constants (fixed by reference): B=2, N=8192, C=80
constexpr int NB = 2;
constexpr int NN = 8192;
constexpr int NC = 80;

// d_out layout (floats), in reference return order:
// boxes[B,N,4], max_scores[B,N], labels[B,N], keep[B,N], all_scores[B,N,C]
constexpr size_t OFF_BOXES  = 0;
constexpr size_t OFF_SCORES = (size_t)NB * NN * 4;            // 65536
constexpr size_t OFF_LABELS = OFF_SCORES + (size_t)NB * NN;   // 81920
constexpr size_t OFF_KEEP   = OFF_LABELS + (size_t)NB * NN;   // 98304
constexpr size_t OFF_ALL    = OFF_KEEP + (size_t)NB * NN;     // 114688

// d_ws layout
constexpr size_t WS_KEYS  = 0;                                  // B*N u64
constexpr size_t WS_VBYTE = WS_KEYS + (size_t)NB * NN * 8;      // B*N u8
constexpr size_t WS_ORDER = WS_VBYTE + (size_t)NB * NN;         // B*N i32
constexpr size_t WS_SBOX  = WS_ORDER + (size_t)NB * NN * 4;     // B*N float4
constexpr size_t WS_VBITS = WS_SBOX + (size_t)NB * NN * 16;     // B*128 u64
constexpr size_t WS_MASK  = WS_VBITS + (size_t)NB * 128 * 8;    // B*N*128 u64
constexpr size_t WS_TOTAL = WS_MASK + (size_t)NB * NN * 128 * 8; // ~17.25 MB

// IoU exactly mirroring the numpy op order; contraction off so f32 rounding
// matches numpy bit-for-bit (keep bits tolerate no error).
__device__ inline float iou_pair(const float4 p, const float4 q) {
#pragma clang fp contract(off)
  float areaA = (p.z - p.x) * (p.w - p.y);
  float areaB = (q.z - q.x) * (q.w - q.y);
  float ix1 = fmaxf(p.x, q.x);
  float iy1 = fmaxf(p.y, q.y);
  float ix2 = fminf(p.z, q.z);
  float iy2 = fminf(p.w, q.w);
  float inter = fmaxf(ix2 - ix1, 0.0f) * fmaxf(iy2 - iy1, 0.0f);
  float uni = areaA + areaB - inter;
  return inter / fmaxf(uni, 1e-9f);
}

__device__ inline float clip01(float v) { return fminf(fmaxf(v, 0.0f), 1.0f); }

// One wave per (b,n): sigmoid all 80 classes, max/argmax (first-index ties),
// box decode, validity, sort key.
__global__ __launch_bounds__(256) void decode_kernel(
    const float* __restrict__ logits, const float4* __restrict__ deltas,
    const float4* __restrict__ anchors, float4* __restrict__ boxes_out,
    float* __restrict__ scores_out, float* __restrict__ labels_out,
    float* __restrict__ all_out, unsigned long long* __restrict__ keys,
    unsigned char* __restrict__ vbyte) {
#pragma clang fp contract(off)
  int wid = (blockIdx.x * 256 + threadIdx.x) >> 6;  // 0 .. B*N-1
  int lane = threadIdx.x & 63;
  int n = wid & (NN - 1);
  size_t base = (size_t)wid * NC;

  float x0 = logits[base + lane];
  float sig0 = 1.0f / (1.0f + expf(-x0));
  all_out[base + lane] = sig0;
  float bs = sig0;
  int bidx = lane;
  if (lane < NC - 64) {
    float x1 = logits[base + 64 + lane];
    float sig1 = 1.0f / (1.0f + expf(-x1));
    all_out[base + 64 + lane] = sig1;
    if (sig1 > bs) { bs = sig1; bidx = lane + 64; }  // tie -> smaller idx wins
  }
  for (int off = 32; off; off >>= 1) {
    float os = __shfl_xor(bs, off, 64);
    int oi = __shfl_xor(bidx, off, 64);
    if (os > bs || (os == bs && oi < bidx)) { bs = os; bidx = oi; }
  }
  if (lane == 0) {
    float4 d = deltas[wid];
    float4 a = anchors[n];
    float aw = a.z - a.x, ah = a.w - a.y;
    float acx = a.x + 0.5f * aw, acy = a.y + 0.5f * ah;
    float dw = fminf(d.z, 4.0f), dh = fminf(d.w, 4.0f);
    float pcx = d.x * aw + acx;
    float pcy = d.y * ah + acy;
    float pw = expf(dw) * aw;
    float ph = expf(dh) * ah;
    float4 bx;
    bx.x = clip01(pcx - 0.5f * pw);
    bx.y = clip01(pcy - 0.5f * ph);
    bx.z = clip01(pcx + 0.5f * pw);
    bx.w = clip01(pcy + 0.5f * ph);
    boxes_out[wid] = bx;
    scores_out[wid] = bs;
    labels_out[wid] = (float)bidx;
    float bw = bx.z - bx.x, bh = bx.w - bx.y;
    bool valid = (bs > 0.5f) && (bw > 0.01f) && (bh > 0.01f) &&
                 (bw < 0.99f) && (bh < 0.99f);
    vbyte[wid] = valid ? 1 : 0;
    // score bits monotone (score>0); tie-break: smaller n first under
    // DESCENDING key sort -> use (N-1-n) in low bits.
    keys[wid] = ((unsigned long long)__float_as_uint(bs) << 32) |
                (unsigned int)(NN - 1 - n);
  }
}

// Per-batch bitonic sort (descending) of 8192 u64 keys in LDS; then emit
// order[], gathered sorted boxes, and valid bitmask in sorted order.
__global__ __launch_bounds__(1024) void sort_kernel(
    const unsigned long long* __restrict__ keys_in,
    const float4* __restrict__ boxes, const unsigned char* __restrict__ vbyte,
    int* __restrict__ order, float4* __restrict__ sbox,
    unsigned long long* __restrict__ vbits) {
  __shared__ unsigned long long sk[NN];  // 64 KiB
  int b = blockIdx.x, tid = threadIdx.x;
  for (int p = tid; p < NN; p += 1024) sk[p] = keys_in[(size_t)b * NN + p];
  __syncthreads();
  for (int k = 2; k <= NN; k <<= 1) {
    for (int j = k >> 1; j > 0; j >>= 1) {
      for (int i = tid; i < NN; i += 1024) {
        int ixj = i ^ j;
        if (ixj > i) {
          unsigned long long a = sk[i], c = sk[ixj];
          bool up = (i & k) == 0;  // descending region
          if (up ? (a < c) : (a > c)) { sk[i] = c; sk[ixj] = a; }
        }
      }
      __syncthreads();
    }
  }
  for (int p = tid; p < NN; p += 1024) {
    unsigned long long key = sk[p];
    int idx = (NN - 1) - (int)(unsigned int)(key & 0xffffffffull);
    order[(size_t)b * NN + p] = idx;
    sbox[(size_t)b * NN + p] = boxes[(size_t)b * NN + idx];
    unsigned long long ball = __ballot(vbyte[(size_t)b * NN + idx] != 0);
    if ((tid & 63) == 0) vbits[b * 128 + (p >> 6)] = ball;
  }
}

// 64x64 tile of the (sorted-order) suppression matrix: bit j set in row i's
// word iff j>i and IoU>0.5. Upper triangle only.
__global__ __launch_bounds__(64) void build_kernel(
    const float4* __restrict__ sbox, unsigned long long* __restrict__ mask) {
  int bx = blockIdx.x, by = blockIdx.y, b = blockIdx.z;
  if (bx < by) return;
  int lane = threadIdx.x;
  __shared__ float4 cb[64];
  cb[lane] = sbox[(size_t)b * NN + bx * 64 + lane];
  __syncthreads();
  int i = by * 64 + lane;
  float4 rb = sbox[(size_t)b * NN + i];
  unsigned long long word = 0;
  int j0 = (bx == by) ? lane + 1 : 0;
  for (int jj = j0; jj < 64; ++jj)
    if (iou_pair(rb, cb[jj]) > 0.5f) word |= 1ull << jj;
  mask[((size_t)b * NN + i) * 128 + bx] = word;
}

// Sequential greedy reduce v2: one 1024-thread block per batch.
// remv[] lives in LDS. Wave 0 runs the serial greedy bit-loop per 64-chunk
// (uniform values, v_readlane broadcast, diag words software-pipelined 2
// chunks ahead into registers). All 16 waves then OR the newly-kept rows'
// future mask words into remv (coalesced loads, 8-way LDS atomicOr).
__global__ __launch_bounds__(1024) void reduce_kernel(
    const unsigned long long* __restrict__ mask,
    const unsigned long long* __restrict__ vbits,
    const int* __restrict__ order, float* __restrict__ keep_out) {
  int b = blockIdx.x, tid = threadIdx.x;
  int lane = tid & 63;
  bool w0 = tid < 64;
  __shared__ unsigned long long s_remv[128];
  __shared__ unsigned long long s_keep[128];
  __shared__ unsigned long long s_vbits[128];
  __shared__ int s_rowlist[64];
  __shared__ int s_nk;
  const unsigned long long* mb = mask + (size_t)b * NN * 128;

  for (int w = tid; w < 128; w += 1024) {
    s_remv[w] = 0ull;
    s_vbits[w] = vbits[b * 128 + w];
  }
  // Software-pipelined diagonal-word prefetch (wave 0): dwA = chunk c,
  // dwB = chunk c+1; issue c+2 at the top of each iteration.
  unsigned long long dwA = 0, dwB = 0;
  if (w0) {
    dwA = mb[(size_t)lane * 128 + 0];
    dwB = mb[(size_t)(64 + lane) * 128 + 1];
  }
  __syncthreads();

  for (int c = 0; c < 128; ++c) {
    if (w0) {
      unsigned long long dwC = 0;
      if (c + 2 < 128)
        dwC = mb[(size_t)((c + 2) * 64 + lane) * 128 + (c + 2)];
      unsigned long long rm = s_remv[c];
      unsigned long long cand = s_vbits[c] & ~rm;  // uniform across wave 0
      unsigned int dl = (unsigned int)dwA;
      unsigned int dh = (unsigned int)(dwA >> 32);
      unsigned long long kept = 0;
      while (cand) {  // uniform loop; bi is wave-uniform -> readlane is legal
        int bi = __builtin_ctzll(cand);
        unsigned long long rd =
            ((unsigned long long)(unsigned int)
                 __builtin_amdgcn_readlane((int)dh, bi) << 32) |
            (unsigned int)__builtin_amdgcn_readlane((int)dl, bi);
        kept |= 1ull << bi;
        cand = (cand - 1) & cand & ~rd;
      }
      if (lane == 0) {
        s_keep[c] = kept;
        s_nk = __popcll(kept);
      }
      if ((kept >> lane) & 1) {
        int pos = __popcll(kept & ((1ull << lane) - 1ull));
        s_rowlist[pos] = c * 64 + lane;
      }
      dwA = dwB;
      dwB = dwC;
    }
    __syncthreads();
    int nk = s_nk;
    if (nk > 0) {
      int w = tid & 127;   // word index
      int g = tid >> 7;    // row slot 0..7
      if (w > c) {
        unsigned long long acc = 0;
        for (int k = g; k < nk; k += 8)
          acc |= mb[(size_t)s_rowlist[k] * 128 + w];
        if (acc) atomicOr(&s_remv[w], acc);
      }
    }
    __syncthreads();
  }

  // scatter keep flags back to original anchor order (all 1024 threads)
  for (int p = tid; p < NN; p += 1024) {
    int orig = order[(size_t)b * NN + p];
    keep_out[(size_t)b * NN + orig] =
        ((s_keep[p >> 6] >> (p & 63)) & 1) ? 1.0f : 0.0f;
  }
}

// Slow-but-correct fallback if d_ws can't hold the 16 MB mask: classic
// iterative greedy NMS, one block per batch.
__global__ __launch_bounds__(1024) void nms_fallback(
    const float4* __restrict__ sbox, const unsigned long long* __restrict__ vbits,
    const int* __restrict__ order, float* __restrict__ keep_out) {
  int b = blockIdx.x, tid = threadIdx.x;
  __shared__ unsigned long long dead[128];
  __shared__ int s_next;
  __shared__ float4 s_box;
  for (int w = tid; w < 128; w += 1024) dead[w] = ~vbits[b * 128 + w];
  for (int p = tid; p < NN; p += 1024)
    keep_out[(size_t)b * NN + order[(size_t)b * NN + p]] = 0.0f;
  __syncthreads();
  int i = 0;
  while (true) {
    if (tid == 0) {
      int nxt = NN;
      int w = i >> 6;
      unsigned long long live = ~dead[w] & (~0ull << (i & 63));
      while (true) {
        if (live) { nxt = w * 64 + __builtin_ctzll(live); break; }
        if (++w >= 128) break;
        live = ~dead[w];
      }
      s_next = nxt;
      if (nxt < NN) {
        s_box = sbox[(size_t)b * NN + nxt];
        keep_out[(size_t)b * NN + order[(size_t)b * NN + nxt]] = 1.0f;
      }
    }
    __syncthreads();
    i = s_next;
    if (i >= NN) break;
    float4 kb = s_box;
    for (int j = i + 1 + tid; j < NN; j += 1024) {
      if (iou_pair(kb, sbox[(size_t)b * NN + j]) > 0.5f)
        atomicOr(&dead[j >> 6], 1ull << (j & 63));
    }
    __syncthreads();
    i = i + 1;
  }
}

extern "C" void kernel_launch(void* const* d_in, const int* in_sizes, int n_in,
                              void* d_out, int out_size, void* d_ws, size_t ws_size,
                              hipStream_t stream) {
  const float* logits = (const float*)d_in[0];
  const float4* deltas = (const float4*)d_in[1];
  const float4* anchors = (const float4*)d_in[2];
  float* out = (float*)d_out;
  float4* boxes_out = (float4*)(out + OFF_BOXES);
  float* scores_out = out + OFF_SCORES;
  float* labels_out = out + OFF_LABELS;
  float* keep_out = out + OFF_KEEP;
  float* all_out = out + OFF_ALL;

  char* ws = (char*)d_ws;
  unsigned long long* keys = (unsigned long long*)(ws + WS_KEYS);
  unsigned char* vbyte = (unsigned char*)(ws + WS_VBYTE);
  int* order = (int*)(ws + WS_ORDER);
  float4* sbox = (float4*)(ws + WS_SBOX);
  unsigned long long* vbits = (unsigned long long*)(ws + WS_VBITS);
  unsigned long long* mask = (unsigned long long*)(ws + WS_MASK);

  decode_kernel<<<dim3(NB * NN / 4), dim3(256), 0, stream>>>(
      logits, deltas, anchors, boxes_out, scores_out, labels_out, all_out,
      keys, vbyte);
  sort_kernel<<<dim3(NB), dim3(1024), 0, stream>>>(
      keys, (const float4*)boxes_out, vbyte, order, sbox, vbits);
  if (ws_size >= WS_TOTAL) {
    build_kernel<<<dim3(128, 128, NB), dim3(64), 0, stream>>>(sbox, mask);
    reduce_kernel<<<dim3(NB), dim3(1024), 0, stream>>>(mask, vbits, order, keep_out);
  } else {
    nms_fallback<<<dim3(NB), dim3(1024), 0, stream>>>(sbox, vbits, order, keep_out);
  }
}